// Round 14
// baseline (1273.576 us; speedup 1.0000x reference)
//
#include <hip/hip_runtime.h>
#include <cstdint>
#include <cstddef>

// Problem constants (Swin window attention)
#define B_WIN   2048
#define N_TOK   64
#define C_DIM   512
#define H_HEADS 16
#define D_HEAD  32
#define K_DIM   512
#define M_ROWS  (B_WIN * 64)   // 131072

// Tiled operand layout for GEMM operands (bf16), 128-row granules:
//   T[mb][kt][s][r][e]  mb=row>>7, kt=k>>5, s=(k>>3)&3, r=row&127, e=k&7
//   flat elem = mb*65536 + kt*4096 + s*1024 + r*8 + e

typedef __bf16 bf16x8 __attribute__((ext_vector_type(8)));
typedef float  f32x4  __attribute__((ext_vector_type(4)));
typedef unsigned short u16x8 __attribute__((ext_vector_type(8)));

__device__ __forceinline__ unsigned short f2bf_rn(float f) {
    unsigned u = __float_as_uint(f);
    u += 0x7fffu + ((u >> 16) & 1u);
    return (unsigned short)(u >> 16);
}
__device__ __forceinline__ float bf2f(unsigned short h) {
    return __uint_as_float(((unsigned)h) << 16);
}
__device__ __forceinline__ void gload16(const void* g, void* l) {
    __builtin_amdgcn_global_load_lds(
        (const __attribute__((address_space(1))) void*)g,
        (__attribute__((address_space(3))) void*)l,
        16, 0, 0);
}

// ---------------------------------------------------------------------------
// prep: fused {xsplit | qkv wsplit | bias_expand} (grid-partitioned).
// ---------------------------------------------------------------------------
__global__ __launch_bounds__(256) void prep_kernel(
    const float* __restrict__ x,
    unsigned short* __restrict__ Xh,
    unsigned short* __restrict__ Xl,
    const float* __restrict__ qkv_w,
    unsigned short* __restrict__ qwTh,
    unsigned short* __restrict__ qwTl,
    const float* __restrict__ bias_table,
    const int* __restrict__ rel_index,
    float* __restrict__ bias_hn)
{
    const int blk = blockIdx.x;
    if (blk < 32768) {
        // ---- xsplit ----
        size_t e8 = ((size_t)blk * 256 + threadIdx.x) * 8;
        const int mb = (int)(e8 >> 16);
        const int w  = (int)(e8 & 65535);
        const int kt = w >> 12;
        const int s  = (w >> 10) & 3;
        const int r  = (w >> 3) & 127;
        const int m  = mb * 128 + r;
        const int k  = kt * 32 + s * 8;
        const float* src = &x[(size_t)m * 512 + k];
        float4 f0 = *reinterpret_cast<const float4*>(src);
        float4 f1 = *reinterpret_cast<const float4*>(src + 4);
        float fv[8] = {f0.x, f0.y, f0.z, f0.w, f1.x, f1.y, f1.z, f1.w};
        u16x8 hi, lo;
#pragma unroll
        for (int j = 0; j < 8; ++j) {
            unsigned short h = f2bf_rn(fv[j]);
            hi[j] = h;
            lo[j] = f2bf_rn(fv[j] - bf2f(h));
        }
        *reinterpret_cast<u16x8*>(&Xh[e8]) = hi;
        *reinterpret_cast<u16x8*>(&Xl[e8]) = lo;
    } else if (blk < 33152) {
        // ---- wsplit qkv_w (Ncols = 1536) ----
        size_t e8 = ((size_t)(blk - 32768) * 256 + threadIdx.x) * 8;
        const int mb = (int)(e8 >> 16);
        const int ww = (int)(e8 & 65535);
        const int kt = ww >> 12;
        const int s  = (ww >> 10) & 3;
        const int r  = (ww >> 3) & 127;
        const int n  = mb * 128 + r;
        const int k  = kt * 32 + s * 8;
        u16x8 hi, lo;
#pragma unroll
        for (int j = 0; j < 8; ++j) {
            float v = qkv_w[(size_t)(k + j) * 1536 + n];
            unsigned short h = f2bf_rn(v);
            hi[j] = h;
            lo[j] = f2bf_rn(v - bf2f(h));
        }
        *reinterpret_cast<u16x8*>(&qwTh[e8]) = hi;
        *reinterpret_cast<u16x8*>(&qwTl[e8]) = lo;
    } else {
        // ---- bias expand ----
        int tid = (blk - 33152) * 256 + threadIdx.x;
        int h  = tid >> 12;
        int ij = tid & 4095;
        bias_hn[tid] = bias_table[rel_index[ij] * H_HEADS + h];
    }
}

// ---------------------------------------------------------------------------
// wsplit (proj_w only; must run after attn because of its parking region)
// ---------------------------------------------------------------------------
__global__ __launch_bounds__(256) void wsplit_kernel(
    const float* __restrict__ w,
    unsigned short* __restrict__ wTh,
    unsigned short* __restrict__ wTl,
    int Ncols)
{
    size_t e8 = ((size_t)blockIdx.x * 256 + threadIdx.x) * 8;
    const int mb = (int)(e8 >> 16);
    const int ww = (int)(e8 & 65535);
    const int kt = ww >> 12;
    const int s  = (ww >> 10) & 3;
    const int r  = (ww >> 3) & 127;
    const int n  = mb * 128 + r;
    const int k  = kt * 32 + s * 8;
    u16x8 hi, lo;
#pragma unroll
    for (int j = 0; j < 8; ++j) {
        float v = w[(size_t)(k + j) * Ncols + n];
        unsigned short h = f2bf_rn(v);
        hi[j] = h;
        lo[j] = f2bf_rn(v - bf2f(h));
    }
    *reinterpret_cast<u16x8*>(&wTh[e8]) = hi;
    *reinterpret_cast<u16x8*>(&wTl[e8]) = lo;
}

// ---------------------------------------------------------------------------
// bf16x3-split MFMA GEMM, 256x128 tile, BK=32, 16 steps, 8 waves (512 thr).
// R14: acc[8][2] (64 regs) + B-frags DIRECT from L2 (weights, no LDS stage)
// -> total regs <=128 (launch_bounds(512,4)) and LDS 64KB -> 2 blocks/CU:
// two blocks interleave barrier phases (the R7 mechanism) while keeping
// 256-row A-reuse. Sync skeleton identical to the proven R12/R13 loop.
// B loads are issued BEFORE the A-stage gloads (sched_barrier pin) so the
// compiler's register wait on B leaves the A stage in flight (in-order vmcnt).
// ---------------------------------------------------------------------------
__global__ __launch_bounds__(512, 4) void gemm_mfma_kernel(
    const unsigned short* __restrict__ ATh,
    const unsigned short* __restrict__ ATl,
    const unsigned short* __restrict__ BTh,
    const unsigned short* __restrict__ BTl,
    int mode,
    float* __restrict__ qkv_out,
    const float* __restrict__ bias,
    float* __restrict__ out,
    int Ncols_out,
    int nb_grid)                 // blocks along n (Ncols/128)
{
    extern __shared__ __align__(16) unsigned short L[];  // 32768 elems = 64 KiB
    // buffer bi at bi*16384 elems: Ah +0 (8192), Al +8192

    const int t    = threadIdx.x;
    const int lane = t & 63;
    const int wave = t >> 6;             // 0..7
    const int lg   = lane >> 4;          // k-octet 0..3
    const int lr   = lane & 15;          // row within fragment
    const int wrow = (wave >> 2) * 128;  // 0,128
    const int wcol = (wave & 3) * 32;    // 0,32,64,96

    const int lin = blockIdx.x + gridDim.x * blockIdx.y;
    const int nwg = gridDim.x * gridDim.y;
    const int cpx = nwg >> 3;
    const int swz = (lin & 7) * cpx + (lin >> 3);
    const int m0  = (swz / nb_grid) * 256;
    const int n0  = (swz % nb_grid) * 128;
    const int mb0 = m0 >> 7;             // first 128-row granule of A
    const int nb0 = n0 >> 7;             // the (single) 128-row granule of B

    f32x4 acc[8][2];
#pragma unroll
    for (int i = 0; i < 8; ++i)
#pragma unroll
        for (int j = 0; j < 2; ++j) acc[i][j] = (f32x4){0.f, 0.f, 0.f, 0.f};

    // stage A (hi+lo) for K-step kt into buffer bi: 4 gloads/thread (32 KiB)
    auto stageA = [&](int kt, int bi) {
        const int bufbase = bi * 16384;
#pragma unroll
        for (int i = 0; i < 2; ++i) {
            const int c = i * 512 + t;        // chunk 0..1023, wave-contiguous
            const int r = c & 255;            // row in 256-tile
            const int s = c >> 8;             // k-octet pair 0..3
            const size_t gA = (size_t)(mb0 + (r >> 7)) * 65536
                            + (size_t)kt * 4096 + s * 1024 + (r & 127) * 8;
            const int lo = bufbase + s * 2048 + r * 8;   // wave-uniform + lane*8
            gload16(&ATh[gA], &L[lo]);
            gload16(&ATl[gA], &L[lo + 8192]);
        }
    };

    stageA(0, 0);
    asm volatile("s_waitcnt vmcnt(0)" ::: "memory");
    __builtin_amdgcn_sched_barrier(0);
    __builtin_amdgcn_s_barrier();
    __builtin_amdgcn_sched_barrier(0);

#pragma unroll 2
    for (int ks = 0; ks < 16; ++ks) {
        const int cur = ks & 1;

        // B-fragments direct from global (L2-resident weights), issued FIRST
        bf16x8 bh[2], bl[2];
#pragma unroll
        for (int ni = 0; ni < 2; ++ni) {
            const size_t gB = (size_t)nb0 * 65536 + (size_t)ks * 4096
                            + lg * 1024 + (wcol + ni * 16 + lr) * 8;
            bh[ni] = *reinterpret_cast<const bf16x8*>(&BTh[gB]);
            bl[ni] = *reinterpret_cast<const bf16x8*>(&BTl[gB]);
        }
        __builtin_amdgcn_sched_barrier(0);   // pin: B loads precede A stage
        if (ks + 1 < 16) stageA(ks + 1, cur ^ 1);
        const int bb = cur * 16384;

        __builtin_amdgcn_s_setprio(1);
#pragma unroll
        for (int mi = 0; mi < 8; ++mi) {
            const int aoff = bb + lg * 2048 + (wrow + mi * 16 + lr) * 8;
            bf16x8 ah = *reinterpret_cast<const bf16x8*>(&L[aoff]);
            bf16x8 al = *reinterpret_cast<const bf16x8*>(&L[aoff + 8192]);
            // per-acc order hh -> hl -> lh (bit-identical to prior rounds)
#pragma unroll
            for (int ni = 0; ni < 2; ++ni)
                acc[mi][ni] = __builtin_amdgcn_mfma_f32_16x16x32_bf16(ah, bh[ni], acc[mi][ni], 0, 0, 0);
#pragma unroll
            for (int ni = 0; ni < 2; ++ni)
                acc[mi][ni] = __builtin_amdgcn_mfma_f32_16x16x32_bf16(ah, bl[ni], acc[mi][ni], 0, 0, 0);
#pragma unroll
            for (int ni = 0; ni < 2; ++ni)
                acc[mi][ni] = __builtin_amdgcn_mfma_f32_16x16x32_bf16(al, bh[ni], acc[mi][ni], 0, 0, 0);
        }
        __builtin_amdgcn_s_setprio(0);

        // drain own A-stage (issued ~a full MFMA cluster ago) + barrier
        asm volatile("s_waitcnt vmcnt(0)" ::: "memory");
        __builtin_amdgcn_sched_barrier(0);
        __builtin_amdgcn_s_barrier();
        __builtin_amdgcn_sched_barrier(0);
    }

    // C/D layout: col = lane&15, row = (lane>>4)*4 + reg   [m89-verified]
    if (mode == 0) {
#pragma unroll
        for (int mi = 0; mi < 8; ++mi)
#pragma unroll
            for (int ni = 0; ni < 2; ++ni) {
                const int col  = n0 + wcol + ni * 16 + lr;
                const int tsel = col >> 9;
                const int h    = (col >> 5) & 15;
                const int dd   = col & 31;
#pragma unroll
                for (int reg = 0; reg < 4; ++reg) {
                    const int row = m0 + wrow + mi * 16 + lg * 4 + reg;
                    const int b = row >> 6, n = row & 63;
                    qkv_out[((((size_t)tsel * B_WIN + b) * H_HEADS + h) * N_TOK + n) * D_HEAD + dd]
                        = acc[mi][ni][reg];
                }
            }
    } else {
#pragma unroll
        for (int mi = 0; mi < 8; ++mi)
#pragma unroll
            for (int ni = 0; ni < 2; ++ni) {
                const int col = n0 + wcol + ni * 16 + lr;
                const float pb = bias[col];
#pragma unroll
                for (int reg = 0; reg < 4; ++reg) {
                    const int row = m0 + wrow + mi * 16 + lg * 4 + reg;
                    out[(size_t)row * Ncols_out + col] = acc[mi][ni][reg] + pb;
                }
            }
    }
}

// ---------------------------------------------------------------------------
// MFMA window attention (unchanged from R6/R7 — proven)
// ---------------------------------------------------------------------------
__global__ __launch_bounds__(256, 4) void attn_kernel(
    const float* __restrict__ qkv,        // [3][B][H][N][D]
    const float* __restrict__ bias_hn,    // [H][64][64]
    float* __restrict__ attn_map,         // [B][H][64][64]
    unsigned short* __restrict__ avh,     // tiled bf16 hi
    unsigned short* __restrict__ avl)     // tiled bf16 lo
{
    __shared__ __align__(16) unsigned short SM[14848];
    constexpr int QH = 0, QL = 2560, KH = 5120, KL = 7680;   // [64][40]
    constexpr int PH = 0, PL = 4608;                         // [64][72]
    constexpr int VTH = 10240, VTL = 12544;                  // [32][72]

    const int bh   = blockIdx.x;
    const int b    = bh >> 4;
    const int h    = bh & 15;
    const int t    = threadIdx.x;
    const int lane = t & 63;
    const int wv   = t >> 6;
    const int lg   = lane >> 4;
    const int lr   = lane & 15;

    const size_t plane = (size_t)B_WIN * H_HEADS * N_TOK * D_HEAD;
    const size_t base  = (size_t)bh * (N_TOK * D_HEAD);
    const float* qg = qkv + base;
    const float* kg = qkv + plane + base;
    const float* vg = qkv + 2 * plane + base;

    {
        const int r  = t >> 2;
        const int c0 = (t & 3) * 8;
        float4 a0 = *reinterpret_cast<const float4*>(&qg[r * 32 + c0]);
        float4 a1 = *reinterpret_cast<const float4*>(&qg[r * 32 + c0 + 4]);
        float qv[8] = {a0.x, a0.y, a0.z, a0.w, a1.x, a1.y, a1.z, a1.w};
        u16x8 hi, lo;
#pragma unroll
        for (int j = 0; j < 8; ++j) {
            unsigned short hh = f2bf_rn(qv[j]);
            hi[j] = hh; lo[j] = f2bf_rn(qv[j] - bf2f(hh));
        }
        *reinterpret_cast<u16x8*>(&SM[QH + r * 40 + c0]) = hi;
        *reinterpret_cast<u16x8*>(&SM[QL + r * 40 + c0]) = lo;

        float4 k0 = *reinterpret_cast<const float4*>(&kg[r * 32 + c0]);
        float4 k1 = *reinterpret_cast<const float4*>(&kg[r * 32 + c0 + 4]);
        float kv[8] = {k0.x, k0.y, k0.z, k0.w, k1.x, k1.y, k1.z, k1.w};
#pragma unroll
        for (int j = 0; j < 8; ++j) {
            unsigned short hh = f2bf_rn(kv[j]);
            hi[j] = hh; lo[j] = f2bf_rn(kv[j] - bf2f(hh));
        }
        *reinterpret_cast<u16x8*>(&SM[KH + r * 40 + c0]) = hi;
        *reinterpret_cast<u16x8*>(&SM[KL + r * 40 + c0]) = lo;

        float4 v0 = *reinterpret_cast<const float4*>(&vg[r * 32 + c0]);
        float4 v1 = *reinterpret_cast<const float4*>(&vg[r * 32 + c0 + 4]);
        float vv[8] = {v0.x, v0.y, v0.z, v0.w, v1.x, v1.y, v1.z, v1.w};
#pragma unroll
        for (int u = 0; u < 8; ++u) {
            const int d = c0 + u;
            unsigned short hh = f2bf_rn(vv[u]);
            SM[VTH + d * 72 + r] = hh;
            SM[VTL + d * 72 + r] = f2bf_rn(vv[u] - bf2f(hh));
        }
    }
    __syncthreads();

    float bias[4][4];
#pragma unroll
    for (int reg = 0; reg < 4; ++reg)
#pragma unroll
        for (int c = 0; c < 4; ++c)
            bias[reg][c] = bias_hn[(h << 12) + ((wv * 16 + lg * 4 + reg) << 6) + c * 16 + lr];

    const int ar = wv * 16 + lr;
    bf16x8 qa_h = *reinterpret_cast<const bf16x8*>(&SM[QH + ar * 40 + lg * 8]);
    bf16x8 qa_l = *reinterpret_cast<const bf16x8*>(&SM[QL + ar * 40 + lg * 8]);
    f32x4 S[4];
#pragma unroll
    for (int c = 0; c < 4; ++c) {
        const int br = c * 16 + lr;
        bf16x8 kb_h = *reinterpret_cast<const bf16x8*>(&SM[KH + br * 40 + lg * 8]);
        bf16x8 kb_l = *reinterpret_cast<const bf16x8*>(&SM[KL + br * 40 + lg * 8]);
        f32x4 s = (f32x4){0.f, 0.f, 0.f, 0.f};
        s = __builtin_amdgcn_mfma_f32_16x16x32_bf16(qa_h, kb_h, s, 0, 0, 0);
        s = __builtin_amdgcn_mfma_f32_16x16x32_bf16(qa_h, kb_l, s, 0, 0, 0);
        s = __builtin_amdgcn_mfma_f32_16x16x32_bf16(qa_l, kb_h, s, 0, 0, 0);
        S[c] = s;
    }
    __syncthreads();   // Q/K region dead -> reusable for P

    const float scale = 0.1767766952966369f;  // 32^-0.5
    float p[4][4], mx[4], sm[4];
#pragma unroll
    for (int reg = 0; reg < 4; ++reg) mx[reg] = -1e30f;
#pragma unroll
    for (int reg = 0; reg < 4; ++reg)
#pragma unroll
        for (int c = 0; c < 4; ++c) {
            float s = fmaf(S[c][reg], scale, bias[reg][c]);
            p[reg][c] = s;
            mx[reg] = fmaxf(mx[reg], s);
        }
#pragma unroll
    for (int reg = 0; reg < 4; ++reg) {
        mx[reg] = fmaxf(mx[reg], __shfl_xor(mx[reg], 1));
        mx[reg] = fmaxf(mx[reg], __shfl_xor(mx[reg], 2));
        mx[reg] = fmaxf(mx[reg], __shfl_xor(mx[reg], 4));
        mx[reg] = fmaxf(mx[reg], __shfl_xor(mx[reg], 8));
        sm[reg] = 0.f;
    }
#pragma unroll
    for (int reg = 0; reg < 4; ++reg)
#pragma unroll
        for (int c = 0; c < 4; ++c) {
            float e = __expf(p[reg][c] - mx[reg]);
            p[reg][c] = e;
            sm[reg] += e;
        }
#pragma unroll
    for (int reg = 0; reg < 4; ++reg) {
        sm[reg] += __shfl_xor(sm[reg], 1);
        sm[reg] += __shfl_xor(sm[reg], 2);
        sm[reg] += __shfl_xor(sm[reg], 4);
        sm[reg] += __shfl_xor(sm[reg], 8);
        const float inv = 1.0f / sm[reg];
#pragma unroll
        for (int c = 0; c < 4; ++c) p[reg][c] *= inv;
    }

    const size_t amb = (size_t)bh * 4096;
#pragma unroll
    for (int reg = 0; reg < 4; ++reg) {
        const int R = wv * 16 + lg * 4 + reg;
#pragma unroll
        for (int c = 0; c < 4; ++c) {
            const int C = c * 16 + lr;
            const float own = p[reg][c];
            attn_map[amb + R * 64 + C] = own;
            const float mate = __shfl_xor(own, 1);
            if (!(lr & 1)) {
                unsigned short h0 = f2bf_rn(own);
                unsigned short l0 = f2bf_rn(own - bf2f(h0));
                unsigned short h1 = f2bf_rn(mate);
                unsigned short l1 = f2bf_rn(mate - bf2f(h1));
                *reinterpret_cast<unsigned*>(&SM[PH + R * 72 + C]) =
                    (unsigned)h0 | ((unsigned)h1 << 16);
                *reinterpret_cast<unsigned*>(&SM[PL + R * 72 + C]) =
                    (unsigned)l0 | ((unsigned)l1 << 16);
            }
        }
    }
    // no barrier: wave w's PV a-frags read rows 16wv..16wv+15 = its own writes

    f32x4 O[2];
    O[0] = (f32x4){0.f, 0.f, 0.f, 0.f};
    O[1] = (f32x4){0.f, 0.f, 0.f, 0.f};
#pragma unroll
    for (int kk = 0; kk < 2; ++kk) {
        const int pr = wv * 16 + lr;
        bf16x8 pa_h = *reinterpret_cast<const bf16x8*>(&SM[PH + pr * 72 + kk * 32 + lg * 8]);
        bf16x8 pa_l = *reinterpret_cast<const bf16x8*>(&SM[PL + pr * 72 + kk * 32 + lg * 8]);
#pragma unroll
        for (int n = 0; n < 2; ++n) {
            const int vr = n * 16 + lr;
            bf16x8 vb_h = *reinterpret_cast<const bf16x8*>(&SM[VTH + vr * 72 + kk * 32 + lg * 8]);
            bf16x8 vb_l = *reinterpret_cast<const bf16x8*>(&SM[VTL + vr * 72 + kk * 32 + lg * 8]);
            O[n] = __builtin_amdgcn_mfma_f32_16x16x32_bf16(pa_h, vb_h, O[n], 0, 0, 0);
            O[n] = __builtin_amdgcn_mfma_f32_16x16x32_bf16(pa_h, vb_l, O[n], 0, 0, 0);
            O[n] = __builtin_amdgcn_mfma_f32_16x16x32_bf16(pa_l, vb_h, O[n], 0, 0, 0);
        }
    }

    const int mb = b >> 1;
#pragma unroll
    for (int n = 0; n < 2; ++n)
#pragma unroll
        for (int reg = 0; reg < 4; ++reg) {
            const int R  = wv * 16 + lg * 4 + reg;
            const int d  = n * 16 + lr;
            const int rl = (b & 1) * 64 + R;
            const float o = O[n][reg];
            unsigned short oh = f2bf_rn(o);
            unsigned short ol = f2bf_rn(o - bf2f(oh));
            size_t off = (size_t)mb * 65536 + (size_t)h * 4096
                       + (size_t)(d >> 3) * 1024 + (size_t)rl * 8 + (d & 7);
            avh[off] = oh;
            avl[off] = ol;
        }
}

// ---------------------------------------------------------------------------
extern "C" void kernel_launch(void* const* d_in, const int* in_sizes, int n_in,
                              void* d_out, int out_size, void* d_ws, size_t ws_size,
                              hipStream_t stream) {
    const float* x          = (const float*)d_in[0];
    const float* qkv_w      = (const float*)d_in[1];
    const float* proj_w     = (const float*)d_in[2];
    const float* proj_b     = (const float*)d_in[3];
    const float* bias_table = (const float*)d_in[4];
    const int*   rel_index  = (const int*)d_in[5];

    float* out      = (float*)d_out;                           // [131072][512]
    float* attn_map = (float*)d_out + (size_t)M_ROWS * C_DIM;  // [B][H][64][64]

    // d_ws: Xh | Xl (tiled bf16) | qkv fp32
    // avh/avl alias Xh/Xl (dead after QKV GEMM).
    unsigned short* Xh  = (unsigned short*)d_ws;
    unsigned short* Xl  = Xh + (size_t)M_ROWS * 512;
    float*          qkv = (float*)(Xl + (size_t)M_ROWS * 512);
    unsigned short* avh = Xh;
    unsigned short* avl = Xl;

    // parking: qkv_w split -> attn_map region of d_out (dead until attn
    // overwrites it); proj_w split -> qkv head (dead after attn reads qkv);
    // bias_hn -> out head (out written only by the final proj GEMM).
    unsigned short* qwTh = (unsigned short*)attn_map;
    unsigned short* qwTl = qwTh + (size_t)1536 * 512;
    unsigned short* pwTh = (unsigned short*)qkv;
    unsigned short* pwTl = pwTh + (size_t)512 * 512;
    float* bias_hn = out;   // 65536 floats at head of out region

    prep_kernel<<<33408, 256, 0, stream>>>(
        x, Xh, Xl, qkv_w, qwTh, qwTl, bias_table, rel_index, bias_hn);
    gemm_mfma_kernel<<<dim3(12, 512), 512, 65536, stream>>>(
        Xh, Xl, qwTh, qwTl, 0, qkv, nullptr, nullptr, 1536, 12);
    attn_kernel<<<B_WIN * H_HEADS, 256, 0, stream>>>(
        qkv, bias_hn, attn_map, avh, avl);
    wsplit_kernel<<<128, 256, 0, stream>>>(proj_w, pwTh, pwTl, 512);
    gemm_mfma_kernel<<<dim3(4, 512), 512, 65536, stream>>>(
        avh, avl, pwTh, pwTl, 1, nullptr, proj_b, out, 512, 4);
}

// Round 15
// 1055.143 us; speedup vs baseline: 1.2070x; 1.2070x over previous
//
#include <hip/hip_runtime.h>
#include <cstdint>
#include <cstddef>

// Problem constants (Swin window attention)
#define B_WIN   2048
#define N_TOK   64
#define C_DIM   512
#define H_HEADS 16
#define D_HEAD  32
#define K_DIM   512
#define M_ROWS  (B_WIN * 64)   // 131072

// Tiled operand layout for GEMM operands (bf16), 128-row granules:
//   T[mb][kt][s][r][e]  mb=row>>7, kt=k>>5, s=(k>>3)&3, r=row&127, e=k&7
//   flat elem = mb*65536 + kt*4096 + s*1024 + r*8 + e

typedef __bf16 bf16x8 __attribute__((ext_vector_type(8)));
typedef float  f32x4  __attribute__((ext_vector_type(4)));
typedef unsigned short u16x8 __attribute__((ext_vector_type(8)));

__device__ __forceinline__ unsigned short f2bf_rn(float f) {
    unsigned u = __float_as_uint(f);
    u += 0x7fffu + ((u >> 16) & 1u);
    return (unsigned short)(u >> 16);
}
__device__ __forceinline__ float bf2f(unsigned short h) {
    return __uint_as_float(((unsigned)h) << 16);
}
__device__ __forceinline__ void gload16(const void* g, void* l) {
    __builtin_amdgcn_global_load_lds(
        (const __attribute__((address_space(1))) void*)g,
        (__attribute__((address_space(3))) void*)l,
        16, 0, 0);
}

// ---------------------------------------------------------------------------
// prep: fused {xsplit | qkv wsplit | bias_expand} (grid-partitioned).
// ---------------------------------------------------------------------------
__global__ __launch_bounds__(256) void prep_kernel(
    const float* __restrict__ x,
    unsigned short* __restrict__ Xh,
    unsigned short* __restrict__ Xl,
    const float* __restrict__ qkv_w,
    unsigned short* __restrict__ qwTh,
    unsigned short* __restrict__ qwTl,
    const float* __restrict__ bias_table,
    const int* __restrict__ rel_index,
    float* __restrict__ bias_hn)
{
    const int blk = blockIdx.x;
    if (blk < 32768) {
        size_t e8 = ((size_t)blk * 256 + threadIdx.x) * 8;
        const int mb = (int)(e8 >> 16);
        const int w  = (int)(e8 & 65535);
        const int kt = w >> 12;
        const int s  = (w >> 10) & 3;
        const int r  = (w >> 3) & 127;
        const int m  = mb * 128 + r;
        const int k  = kt * 32 + s * 8;
        const float* src = &x[(size_t)m * 512 + k];
        float4 f0 = *reinterpret_cast<const float4*>(src);
        float4 f1 = *reinterpret_cast<const float4*>(src + 4);
        float fv[8] = {f0.x, f0.y, f0.z, f0.w, f1.x, f1.y, f1.z, f1.w};
        u16x8 hi, lo;
#pragma unroll
        for (int j = 0; j < 8; ++j) {
            unsigned short h = f2bf_rn(fv[j]);
            hi[j] = h;
            lo[j] = f2bf_rn(fv[j] - bf2f(h));
        }
        *reinterpret_cast<u16x8*>(&Xh[e8]) = hi;
        *reinterpret_cast<u16x8*>(&Xl[e8]) = lo;
    } else if (blk < 33152) {
        size_t e8 = ((size_t)(blk - 32768) * 256 + threadIdx.x) * 8;
        const int mb = (int)(e8 >> 16);
        const int ww = (int)(e8 & 65535);
        const int kt = ww >> 12;
        const int s  = (ww >> 10) & 3;
        const int r  = (ww >> 3) & 127;
        const int n  = mb * 128 + r;
        const int k  = kt * 32 + s * 8;
        u16x8 hi, lo;
#pragma unroll
        for (int j = 0; j < 8; ++j) {
            float v = qkv_w[(size_t)(k + j) * 1536 + n];
            unsigned short h = f2bf_rn(v);
            hi[j] = h;
            lo[j] = f2bf_rn(v - bf2f(h));
        }
        *reinterpret_cast<u16x8*>(&qwTh[e8]) = hi;
        *reinterpret_cast<u16x8*>(&qwTl[e8]) = lo;
    } else {
        int tid = (blk - 33152) * 256 + threadIdx.x;
        int h  = tid >> 12;
        int ij = tid & 4095;
        bias_hn[tid] = bias_table[rel_index[ij] * H_HEADS + h];
    }
}

// ---------------------------------------------------------------------------
// wsplit (proj_w only; runs after attn because of its parking region)
// ---------------------------------------------------------------------------
__global__ __launch_bounds__(256) void wsplit_kernel(
    const float* __restrict__ w,
    unsigned short* __restrict__ wTh,
    unsigned short* __restrict__ wTl,
    int Ncols)
{
    size_t e8 = ((size_t)blockIdx.x * 256 + threadIdx.x) * 8;
    const int mb = (int)(e8 >> 16);
    const int ww = (int)(e8 & 65535);
    const int kt = ww >> 12;
    const int s  = (ww >> 10) & 3;
    const int r  = (ww >> 3) & 127;
    const int n  = mb * 128 + r;
    const int k  = kt * 32 + s * 8;
    u16x8 hi, lo;
#pragma unroll
    for (int j = 0; j < 8; ++j) {
        float v = w[(size_t)(k + j) * Ncols + n];
        unsigned short h = f2bf_rn(v);
        hi[j] = h;
        lo[j] = f2bf_rn(v - bf2f(h));
    }
    *reinterpret_cast<u16x8*>(&wTh[e8]) = hi;
    *reinterpret_cast<u16x8*>(&wTl[e8]) = lo;
}

// ---------------------------------------------------------------------------
// bf16-split MFMA GEMM, 256x256 tile, BK=32, 16 steps, 8 waves.
// R13-proven 2-buffer skeleton. Template NPASS:
//   NPASS=3 (QKV): A = Xh/Xl, 3 passes; epilogue writes q,k as bf16 and
//                  v as hi/lo bf16 into per-plane [B][H][64][32] arrays.
//   NPASS=2 (proj): A = avh (exact bf16), 2 passes; epilogue fp32 + bias.
// ---------------------------------------------------------------------------
template<int NPASS>
__global__ __launch_bounds__(512, 2) void gemm_mfma_kernel(
    const unsigned short* __restrict__ ATh,
    const unsigned short* __restrict__ ATl,   // null when NPASS==2
    const unsigned short* __restrict__ BTh,
    const unsigned short* __restrict__ BTl,
    unsigned short* __restrict__ qh,          // NPASS==3 outputs
    unsigned short* __restrict__ kh,
    unsigned short* __restrict__ vh,
    unsigned short* __restrict__ vl,
    const float* __restrict__ bias,           // NPASS==2
    float* __restrict__ out,                  // NPASS==2
    int Ncols_out,
    int nb_grid)                              // blocks along n (Ncols/256)
{
    extern __shared__ __align__(16) unsigned short L[];
    constexpr int AH = 0;
    constexpr int AL = 8192;                              // NPASS==3 only
    constexpr int BH = (NPASS == 3) ? 16384 : 8192;
    constexpr int BL = (NPASS == 3) ? 24576 : 16384;
    constexpr int STRIDE = (NPASS == 3) ? 32768 : 24576;

    const int t    = threadIdx.x;
    const int lane = t & 63;
    const int wave = t >> 6;             // 0..7
    const int lg   = lane >> 4;          // k-octet 0..3
    const int lr   = lane & 15;          // row within fragment
    const int wrow = (wave >> 2) * 128;  // 0,128
    const int wcol = (wave & 3) * 64;    // 0,64,128,192

    const int lin = blockIdx.x + gridDim.x * blockIdx.y;
    const int nwg = gridDim.x * gridDim.y;
    const int cpx = nwg >> 3;
    const int swz = (lin & 7) * cpx + (lin >> 3);
    const int m0  = (swz / nb_grid) * 256;
    const int n0  = (swz % nb_grid) * 256;
    const int mb0 = m0 >> 7;
    const int nb0 = n0 >> 7;

    f32x4 acc[8][4];
#pragma unroll
    for (int i = 0; i < 8; ++i)
#pragma unroll
        for (int j = 0; j < 4; ++j) acc[i][j] = (f32x4){0.f, 0.f, 0.f, 0.f};

    auto stage = [&](int kt, int bi) {
        const int bufbase = bi * STRIDE;
#pragma unroll
        for (int i = 0; i < 2; ++i) {
            const int c = i * 512 + t;        // 0..1023
            const int r = c & 255;
            const int s = c >> 8;
            const size_t gA = (size_t)(mb0 + (r >> 7)) * 65536
                            + (size_t)kt * 4096 + s * 1024 + (r & 127) * 8;
            const size_t gB = (size_t)(nb0 + (r >> 7)) * 65536
                            + (size_t)kt * 4096 + s * 1024 + (r & 127) * 8;
            const int lo = bufbase + s * 2048 + r * 8;
            gload16(&ATh[gA], &L[lo + AH]);
            if constexpr (NPASS == 3) gload16(&ATl[gA], &L[lo + AL]);
            gload16(&BTh[gB], &L[lo + BH]);
            gload16(&BTl[gB], &L[lo + BL]);
        }
    };

    stage(0, 0);
    asm volatile("s_waitcnt vmcnt(0)" ::: "memory");
    __builtin_amdgcn_sched_barrier(0);
    __builtin_amdgcn_s_barrier();
    __builtin_amdgcn_sched_barrier(0);

#pragma unroll 2
    for (int ks = 0; ks < 16; ++ks) {
        const int cur = ks & 1;
        if (ks + 1 < 16) stage(ks + 1, cur ^ 1);
        const int bb = cur * STRIDE;

        bf16x8 bh[4], bl[4];
#pragma unroll
        for (int ni = 0; ni < 4; ++ni) {
            const int off = bb + lg * 2048 + (wcol + ni * 16 + lr) * 8;
            bh[ni] = *reinterpret_cast<const bf16x8*>(&L[off + BH]);
            bl[ni] = *reinterpret_cast<const bf16x8*>(&L[off + BL]);
        }
        __builtin_amdgcn_s_setprio(1);
#pragma unroll
        for (int mi = 0; mi < 8; ++mi) {
            const int aoff = bb + lg * 2048 + (wrow + mi * 16 + lr) * 8;
            bf16x8 ah = *reinterpret_cast<const bf16x8*>(&L[aoff + AH]);
#pragma unroll
            for (int ni = 0; ni < 4; ++ni)
                acc[mi][ni] = __builtin_amdgcn_mfma_f32_16x16x32_bf16(ah, bh[ni], acc[mi][ni], 0, 0, 0);
#pragma unroll
            for (int ni = 0; ni < 4; ++ni)
                acc[mi][ni] = __builtin_amdgcn_mfma_f32_16x16x32_bf16(ah, bl[ni], acc[mi][ni], 0, 0, 0);
            if constexpr (NPASS == 3) {
                bf16x8 al = *reinterpret_cast<const bf16x8*>(&L[aoff + AL]);
#pragma unroll
                for (int ni = 0; ni < 4; ++ni)
                    acc[mi][ni] = __builtin_amdgcn_mfma_f32_16x16x32_bf16(al, bh[ni], acc[mi][ni], 0, 0, 0);
            }
        }
        __builtin_amdgcn_s_setprio(0);

        asm volatile("s_waitcnt vmcnt(0)" ::: "memory");
        __builtin_amdgcn_sched_barrier(0);
        __builtin_amdgcn_s_barrier();
        __builtin_amdgcn_sched_barrier(0);
    }

    // C/D layout: col = lane&15, row = (lane>>4)*4 + reg   [m89-verified]
    if constexpr (NPASS == 3) {
#pragma unroll
        for (int mi = 0; mi < 8; ++mi)
#pragma unroll
            for (int ni = 0; ni < 4; ++ni) {
                const int col  = n0 + wcol + ni * 16 + lr;
                const int tsel = col >> 9;          // lane-group uniform
                const int h    = (col >> 5) & 15;
                const int dd   = col & 31;
#pragma unroll
                for (int reg = 0; reg < 4; ++reg) {
                    const int row = m0 + wrow + mi * 16 + lg * 4 + reg;
                    const int b = row >> 6, n = row & 63;
                    const size_t idx = ((((size_t)b * H_HEADS + h) * 64) + n) * 32 + dd;
                    const float v = acc[mi][ni][reg];
                    unsigned short hh = f2bf_rn(v);
                    if (tsel == 0) {
                        qh[idx] = hh;
                    } else if (tsel == 1) {
                        kh[idx] = hh;
                    } else {
                        vh[idx] = hh;
                        vl[idx] = f2bf_rn(v - bf2f(hh));
                    }
                }
            }
    } else {
#pragma unroll
        for (int mi = 0; mi < 8; ++mi)
#pragma unroll
            for (int ni = 0; ni < 4; ++ni) {
                const int col = n0 + wcol + ni * 16 + lr;
                const float pb = bias[col];
#pragma unroll
                for (int reg = 0; reg < 4; ++reg) {
                    const int row = m0 + wrow + mi * 16 + lg * 4 + reg;
                    out[(size_t)row * Ncols_out + col] = acc[mi][ni][reg] + pb;
                }
            }
    }
}

// ---------------------------------------------------------------------------
// MFMA window attention. q,k arrive as bf16 (QK^T = 1 exact pass); v arrives
// hi/lo (PV = 3-pass split). av emitted bf16-hi only (tiled, feeds proj).
// LDS regions disjoint (37.9 KB) -> the pre-P barrier is dropped.
// ---------------------------------------------------------------------------
__global__ __launch_bounds__(256, 4) void attn_kernel(
    const unsigned short* __restrict__ qh,   // [B][H][64][32] bf16
    const unsigned short* __restrict__ kh,
    const unsigned short* __restrict__ vh,
    const unsigned short* __restrict__ vl,
    const float* __restrict__ bias_hn,       // [H][64][64]
    float* __restrict__ attn_map,            // [B][H][64][64]
    unsigned short* __restrict__ avh)        // tiled bf16 hi
{
    __shared__ __align__(16) unsigned short SM[18944];
    constexpr int VTH = 0, VTL = 2304;       // [32 d][72 r]
    constexpr int QS  = 4608, KS = 7168;     // [64][40]
    constexpr int PH  = 9728, PL = 14336;    // [64][72]

    const int bhid = blockIdx.x;
    const int b    = bhid >> 4;
    const int h    = bhid & 15;
    const int t    = threadIdx.x;
    const int lane = t & 63;
    const int wv   = t >> 6;
    const int lg   = lane >> 4;
    const int lr   = lane & 15;

    const size_t base = (size_t)bhid * 2048;   // 64*32 per (b,h)

    {
        const int r  = t >> 2;
        const int c0 = (t & 3) * 8;
        u16x8 q8 = *reinterpret_cast<const u16x8*>(&qh[base + r * 32 + c0]);
        *reinterpret_cast<u16x8*>(&SM[QS + r * 40 + c0]) = q8;
        u16x8 k8 = *reinterpret_cast<const u16x8*>(&kh[base + r * 32 + c0]);
        *reinterpret_cast<u16x8*>(&SM[KS + r * 40 + c0]) = k8;
        u16x8 vh8 = *reinterpret_cast<const u16x8*>(&vh[base + r * 32 + c0]);
        u16x8 vl8 = *reinterpret_cast<const u16x8*>(&vl[base + r * 32 + c0]);
#pragma unroll
        for (int u = 0; u < 8; ++u) {
            const int d = c0 + u;
            SM[VTH + d * 72 + r] = vh8[u];
            SM[VTL + d * 72 + r] = vl8[u];
        }
    }
    __syncthreads();

    float bias[4][4];
#pragma unroll
    for (int reg = 0; reg < 4; ++reg)
#pragma unroll
        for (int c = 0; c < 4; ++c)
            bias[reg][c] = bias_hn[(h << 12) + ((wv * 16 + lg * 4 + reg) << 6) + c * 16 + lr];

    // QK^T: 1 exact MFMA pass on bf16 q,k
    const int ar = wv * 16 + lr;
    bf16x8 qa = *reinterpret_cast<const bf16x8*>(&SM[QS + ar * 40 + lg * 8]);
    f32x4 S[4];
#pragma unroll
    for (int c = 0; c < 4; ++c) {
        const int br = c * 16 + lr;
        bf16x8 kb = *reinterpret_cast<const bf16x8*>(&SM[KS + br * 40 + lg * 8]);
        f32x4 s = (f32x4){0.f, 0.f, 0.f, 0.f};
        S[c] = __builtin_amdgcn_mfma_f32_16x16x32_bf16(qa, kb, s, 0, 0, 0);
    }
    // no barrier: P region is disjoint from QS/KS/VT

    const float scale = 0.1767766952966369f;  // 32^-0.5
    float p[4][4], mx[4], sm[4];
#pragma unroll
    for (int reg = 0; reg < 4; ++reg) mx[reg] = -1e30f;
#pragma unroll
    for (int reg = 0; reg < 4; ++reg)
#pragma unroll
        for (int c = 0; c < 4; ++c) {
            float s = fmaf(S[c][reg], scale, bias[reg][c]);
            p[reg][c] = s;
            mx[reg] = fmaxf(mx[reg], s);
        }
#pragma unroll
    for (int reg = 0; reg < 4; ++reg) {
        mx[reg] = fmaxf(mx[reg], __shfl_xor(mx[reg], 1));
        mx[reg] = fmaxf(mx[reg], __shfl_xor(mx[reg], 2));
        mx[reg] = fmaxf(mx[reg], __shfl_xor(mx[reg], 4));
        mx[reg] = fmaxf(mx[reg], __shfl_xor(mx[reg], 8));
        sm[reg] = 0.f;
    }
#pragma unroll
    for (int reg = 0; reg < 4; ++reg)
#pragma unroll
        for (int c = 0; c < 4; ++c) {
            float e = __expf(p[reg][c] - mx[reg]);
            p[reg][c] = e;
            sm[reg] += e;
        }
#pragma unroll
    for (int reg = 0; reg < 4; ++reg) {
        sm[reg] += __shfl_xor(sm[reg], 1);
        sm[reg] += __shfl_xor(sm[reg], 2);
        sm[reg] += __shfl_xor(sm[reg], 4);
        sm[reg] += __shfl_xor(sm[reg], 8);
        const float inv = 1.0f / sm[reg];
#pragma unroll
        for (int c = 0; c < 4; ++c) p[reg][c] *= inv;
    }

    const size_t amb = (size_t)bhid * 4096;
#pragma unroll
    for (int reg = 0; reg < 4; ++reg) {
        const int R = wv * 16 + lg * 4 + reg;
#pragma unroll
        for (int c = 0; c < 4; ++c) {
            const int C = c * 16 + lr;
            const float own = p[reg][c];
            attn_map[amb + R * 64 + C] = own;
            const float mate = __shfl_xor(own, 1);
            if (!(lr & 1)) {
                unsigned short h0 = f2bf_rn(own);
                unsigned short l0 = f2bf_rn(own - bf2f(h0));
                unsigned short h1 = f2bf_rn(mate);
                unsigned short l1 = f2bf_rn(mate - bf2f(h1));
                *reinterpret_cast<unsigned*>(&SM[PH + R * 72 + C]) =
                    (unsigned)h0 | ((unsigned)h1 << 16);
                *reinterpret_cast<unsigned*>(&SM[PL + R * 72 + C]) =
                    (unsigned)l0 | ((unsigned)l1 << 16);
            }
        }
    }
    // no barrier: wave wv's PV a-frags read rows 16wv..16wv+15 = its own writes

    f32x4 O[2];
    O[0] = (f32x4){0.f, 0.f, 0.f, 0.f};
    O[1] = (f32x4){0.f, 0.f, 0.f, 0.f};
#pragma unroll
    for (int kk = 0; kk < 2; ++kk) {
        const int pr = wv * 16 + lr;
        bf16x8 pa_h = *reinterpret_cast<const bf16x8*>(&SM[PH + pr * 72 + kk * 32 + lg * 8]);
        bf16x8 pa_l = *reinterpret_cast<const bf16x8*>(&SM[PL + pr * 72 + kk * 32 + lg * 8]);
#pragma unroll
        for (int n = 0; n < 2; ++n) {
            const int vr = n * 16 + lr;
            bf16x8 vb_h = *reinterpret_cast<const bf16x8*>(&SM[VTH + vr * 72 + kk * 32 + lg * 8]);
            bf16x8 vb_l = *reinterpret_cast<const bf16x8*>(&SM[VTL + vr * 72 + kk * 32 + lg * 8]);
            O[n] = __builtin_amdgcn_mfma_f32_16x16x32_bf16(pa_h, vb_h, O[n], 0, 0, 0);
            O[n] = __builtin_amdgcn_mfma_f32_16x16x32_bf16(pa_h, vb_l, O[n], 0, 0, 0);
            O[n] = __builtin_amdgcn_mfma_f32_16x16x32_bf16(pa_l, vb_h, O[n], 0, 0, 0);
        }
    }

    // av store: tiled layout [mb][kt=h][s][r][e], bf16 hi only
    const int mb = b >> 1;
#pragma unroll
    for (int n = 0; n < 2; ++n)
#pragma unroll
        for (int reg = 0; reg < 4; ++reg) {
            const int R  = wv * 16 + lg * 4 + reg;
            const int d  = n * 16 + lr;
            const int rl = (b & 1) * 64 + R;
            size_t off = (size_t)mb * 65536 + (size_t)h * 4096
                       + (size_t)(d >> 3) * 1024 + (size_t)rl * 8 + (d & 7);
            avh[off] = f2bf_rn(O[n][reg]);
        }
}

// ---------------------------------------------------------------------------
extern "C" void kernel_launch(void* const* d_in, const int* in_sizes, int n_in,
                              void* d_out, int out_size, void* d_ws, size_t ws_size,
                              hipStream_t stream) {
    const float* x          = (const float*)d_in[0];
    const float* qkv_w      = (const float*)d_in[1];
    const float* proj_w     = (const float*)d_in[2];
    const float* proj_b     = (const float*)d_in[3];
    const float* bias_table = (const float*)d_in[4];
    const int*   rel_index  = (const int*)d_in[5];

    float* out      = (float*)d_out;                           // [131072][512]
    float* attn_map = (float*)d_out + (size_t)M_ROWS * C_DIM;  // [B][H][64][64]

    // d_ws: Xh | Xl (tiled bf16) | qh | kh | vh | vl (bf16 planes)
    // avh aliases Xh (dead after QKV GEMM).
    const size_t PLANE = (size_t)B_WIN * H_HEADS * 64 * 32;    // 67,108,864
    unsigned short* Xh  = (unsigned short*)d_ws;
    unsigned short* Xl  = Xh + (size_t)M_ROWS * 512;
    unsigned short* qhp = Xl + (size_t)M_ROWS * 512;
    unsigned short* khp = qhp + PLANE;
    unsigned short* vhp = khp + PLANE;
    unsigned short* vlp = vhp + PLANE;
    unsigned short* avh = Xh;

    // parking: qkv_w split -> attn_map region of d_out (dead until attn
    // overwrites it); proj_w split -> qh head (dead after attn reads qh);
    // bias_hn -> out head (read by attn, before proj writes out).
    unsigned short* qwTh = (unsigned short*)attn_map;
    unsigned short* qwTl = qwTh + (size_t)1536 * 512;
    unsigned short* pwTh = qhp;
    unsigned short* pwTl = pwTh + (size_t)512 * 512;
    float* bias_hn = out;

    prep_kernel<<<33408, 256, 0, stream>>>(
        x, Xh, Xl, qkv_w, qwTh, qwTl, bias_table, rel_index, bias_hn);
    gemm_mfma_kernel<3><<<dim3(6, 512), 512, 131072, stream>>>(
        Xh, Xl, qwTh, qwTl, qhp, khp, vhp, vlp, nullptr, nullptr, 1536, 6);
    attn_kernel<<<B_WIN * H_HEADS, 256, 0, stream>>>(
        qhp, khp, vhp, vlp, bias_hn, attn_map, avh);
    wsplit_kernel<<<128, 256, 0, stream>>>(proj_w, pwTh, pwTl, 512);
    gemm_mfma_kernel<2><<<dim3(2, 512), 512, 98304, stream>>>(
        avh, nullptr, pwTh, pwTl, nullptr, nullptr, nullptr, nullptr,
        proj_b, out, 512, 2);
}